// Round 2
// baseline (826.489 us; speedup 1.0000x reference)
//
#include <hip/hip_runtime.h>
#include <math.h>

#define D 256
#define EPSV 1e-8f
#define GAMMAV 0.2f

__device__ __forceinline__ float cleanf(float x) {
    if (isnan(x)) return 0.0f;
    if (isinf(x)) return x > 0.0f ? 10000.0f : 0.0001f;
    return x;
}

// bf16 <-> f32 (RNE on the way down; exact on the way up)
__device__ __forceinline__ unsigned short f2bf(float x) {
    unsigned u = __float_as_uint(x);
    return (unsigned short)((u + 0x7FFFu + ((u >> 16) & 1u)) >> 16);
}
__device__ __forceinline__ float bf2f(unsigned short b) {
    return __uint_as_float(((unsigned)b) << 16);
}

// edge weight: alpha (hops 1,2) or eta (hop 3)
__device__ __forceinline__ float ewgt(int bits, bool eta, float den2i) {
    float a = __int_as_float(bits);
    return eta ? ((a > GAMMAV) ? a * den2i : 0.0f) : a;
}

__device__ __forceinline__ void fma4(float4& acc, float w, ushort4 eb, float4 rw) {
    acc.x += w * bf2f(eb.x) * rw.x;
    acc.y += w * bf2f(eb.y) * rw.y;
    acc.z += w * bf2f(eb.z) * rw.z;
    acc.w += w * bf2f(eb.w) * rw.w;
}
__device__ __forceinline__ void fma4u(float4& acc, float w, ushort4 eb) {
    acc.x += w * bf2f(eb.x);
    acc.y += w * bf2f(eb.y);
    acc.z += w * bf2f(eb.z);
    acc.w += w * bf2f(eb.w);
}

// ---- fused: fp32->bf16 table convert + counting + omega denominator ---
// blocks [0, nbc)        : convert entity_emb fp32 -> bf16
// blocks [nbc, nbc+eb)   : degree counts + omega segment-sum (atomics)

__global__ __launch_bounds__(256) void k_pre(
    const float4* __restrict__ ein, ushort4* __restrict__ eout, int n4, int nbc,
    const int* __restrict__ head, const float* __restrict__ omega,
    const int* __restrict__ iu,
    int* __restrict__ counts_e, int* __restrict__ counts_u,
    float* __restrict__ denom, int E, int IE) {
    if ((int)blockIdx.x < nbc) {
        int i = blockIdx.x * 256 + threadIdx.x;
        if (i < n4) {
            float4 v = ein[i];
            eout[i] = make_ushort4(f2bf(v.x), f2bf(v.y), f2bf(v.z), f2bf(v.w));
        }
    } else {
        int i = (blockIdx.x - nbc) * 256 + threadIdx.x;
        if (i < E) {
            int h = head[i];
            atomicAdd(&counts_e[h], 1);
            atomicAdd(&denom[h], omega[i]);
        } else if (i < E + IE) {
            atomicAdd(&counts_u[iu[i - E]], 1);
        }
    }
}

// ---- single-launch exclusive scan: counts -> packed {off,cnt} + cursor --
// block 0: entities, block 1: users. Per-thread serial chunk + block scan.

__global__ __launch_bounds__(1024) void k_scan(
    const int* __restrict__ ce, int2* __restrict__ oce, int* __restrict__ cure, int nE,
    const int* __restrict__ cu, int2* __restrict__ ocu, int* __restrict__ curu, int nU) {
    const int* cnt; int2* oc; int* cur; int n;
    if (blockIdx.x == 0) { cnt = ce; oc = oce; cur = cure; n = nE; }
    else                 { cnt = cu; oc = ocu; cur = curu; n = nU; }
    int per = (n + 1023) / 1024;
    int t = threadIdx.x;
    int s0 = t * per;
    int s1 = s0 + per; if (s1 > n) s1 = n;
    int sum = 0;
    for (int i = s0; i < s1; ++i) sum += cnt[i];
    __shared__ int tmp[1024];
    tmp[t] = sum;
    __syncthreads();
    for (int o = 1; o < 1024; o <<= 1) {
        int v = (t >= o) ? tmp[t - o] : 0;
        __syncthreads();
        tmp[t] += v;
        __syncthreads();
    }
    int base = tmp[t] - sum;   // exclusive prefix for this thread's chunk
    for (int i = s0; i < s1; ++i) {
        int c = cnt[i];
        oc[i] = make_int2(base, c);
        cur[i] = base;
        base += c;
    }
}

// ---- CSR fill: packed meta + inline alpha + eta denominator -----------

__global__ __launch_bounds__(256) void k_fill_both(
    const int* __restrict__ head, const int* __restrict__ tail,
    const int* __restrict__ etype, const float* __restrict__ omega,
    const int* __restrict__ iu, const int* __restrict__ ii,
    const float* __restrict__ iw,
    const float* __restrict__ denom, float* __restrict__ denom2,
    int* __restrict__ cursor_e, int* __restrict__ cursor_u,
    int2* __restrict__ kg, int2* __restrict__ uc, int E, int IE) {
    int i = blockIdx.x * blockDim.x + threadIdx.x;
    if (i < E) {
        int h = head[i];
        float a = omega[i] / (denom[h] + EPSV);
        int p = atomicAdd(&cursor_e[h], 1);
        int2 m;
        m.x = tail[i] | ((etype[i] - 1) << 20);   // tail < 2^20, rel < 2^5
        m.y = __float_as_int(a);
        kg[p] = m;
        if (a > GAMMAV) atomicAdd(&denom2[h], a);
    } else if (i < E + IE) {
        int e = i - E;
        int u = iu[e];
        int p = atomicAdd(&cursor_u[u], 1);
        int2 m;
        m.x = ii[e];
        m.y = __float_as_int(iw[e]);
        uc[p] = m;
    }
}

// ---- fused hop ---------------------------------------------------------
// waves [0, n_ent)            : entity rows
// waves [n_ent, n_ent+n_users): user rows
// Edge loop batched (x4 ent / x8 usr). sched_barrier(0) between the load
// group and the consume group pins all gathers in flight simultaneously
// (R1 showed the compiler otherwise re-serializes them; VGPR_Count=28).
// Hop-3 residual rows / user base row are issued at the TOP of the row so
// their latency hides under the edge loop.

__global__ __launch_bounds__(256) void k_hop(
    const int2* __restrict__ oc_e, const int2* __restrict__ kg,
    const int2* __restrict__ oc_u, const int2* __restrict__ uc,
    const float* __restrict__ denom2,
    const float* __restrict__ rel,              // fp32 (tiny, cached)
    const unsigned short* __restrict__ src,     // bf16 entity features
    const unsigned short* __restrict__ ent0b,   // bf16 entity_emb (hop3)
    const unsigned short* __restrict__ y1b,     // bf16 hop-1 output (hop3)
    const unsigned short* __restrict__ y2b,     // bf16 hop-2 output (hop3)
    unsigned short* __restrict__ ent_out_b,     // bf16 dst (hops 1,2)
    float* __restrict__ ent_res,                // fp32 dst (hop3)
    const float* __restrict__ user0,
    float* __restrict__ usr_res,
    int n_ent, int n_users, int hop) {
    int row  = (int)((blockIdx.x * (size_t)blockDim.x + threadIdx.x) >> 6);
    int lane = threadIdx.x & 63;
    const ushort4* srcv = (const ushort4*)src;
    const float4*  relv = (const float4*)rel;
    if (row < n_ent) {
        int2 oc = oc_e[row];
        int s = oc.x, deg = oc.y;
        int end = s + deg;
        const bool eta = (hop == 3);
        float den2i = 0.0f;
        ushort4 a0, a1, a2;
        if (eta) {
            den2i = 1.0f / (denom2[row] + EPSV);
            a0 = ((const ushort4*)ent0b)[row * 64 + lane];
            a1 = ((const ushort4*)y1b )[row * 64 + lane];
            a2 = ((const ushort4*)y2b )[row * 64 + lane];
        }
        float4 acc = make_float4(0.f, 0.f, 0.f, 0.f);
        for (int j = s; j < end; j += 4) {
            int e1 = end - 1;
            int j1 = (j + 1 < end) ? j + 1 : e1;
            int j2 = (j + 2 < end) ? j + 2 : e1;
            int j3 = (j + 3 < end) ? j + 3 : e1;
            int2 m0 = kg[j];
            int2 m1 = kg[j1];
            int2 m2 = kg[j2];
            int2 m3 = kg[j3];
            ushort4 eb0 = srcv[(m0.x & 0xFFFFF) * 64 + lane];
            ushort4 eb1 = srcv[(m1.x & 0xFFFFF) * 64 + lane];
            ushort4 eb2 = srcv[(m2.x & 0xFFFFF) * 64 + lane];
            ushort4 eb3 = srcv[(m3.x & 0xFFFFF) * 64 + lane];
            float4 rw0 = relv[(((unsigned)m0.x) >> 20) * 64 + lane];
            float4 rw1 = relv[(((unsigned)m1.x) >> 20) * 64 + lane];
            float4 rw2 = relv[(((unsigned)m2.x) >> 20) * 64 + lane];
            float4 rw3 = relv[(((unsigned)m3.x) >> 20) * 64 + lane];
            __builtin_amdgcn_sched_barrier(0);   // keep all 8 gathers in flight
            float w0 = ewgt(m0.y, eta, den2i);
            float w1 = (j + 1 < end) ? ewgt(m1.y, eta, den2i) : 0.0f;
            float w2 = (j + 2 < end) ? ewgt(m2.y, eta, den2i) : 0.0f;
            float w3 = (j + 3 < end) ? ewgt(m3.y, eta, den2i) : 0.0f;
            fma4(acc, w0, eb0, rw0);
            fma4(acc, w1, eb1, rw1);
            fma4(acc, w2, eb2, rw2);
            fma4(acc, w3, eb3, rw3);
        }
        float cinv = 1.0f / ((deg > 0) ? (float)deg : 1.0f);
        acc.x *= cinv; acc.y *= cinv; acc.z *= cinv; acc.w *= cinv;
        float ss = acc.x * acc.x + acc.y * acc.y + acc.z * acc.z + acc.w * acc.w;
        #pragma unroll
        for (int o = 32; o >= 1; o >>= 1) ss += __shfl_down(ss, o);
        ss = __shfl(ss, 0);
        float nrm = sqrtf(ss);
        float dninv = 1.0f / ((nrm > EPSV) ? nrm : EPSV);
        float4 y;
        y.x = cleanf(acc.x * dninv);
        y.y = cleanf(acc.y * dninv);
        y.z = cleanf(acc.z * dninv);
        y.w = cleanf(acc.w * dninv);
        if (hop == 3) {
            y.x += bf2f(a0.x) + bf2f(a1.x) + bf2f(a2.x);
            y.y += bf2f(a0.y) + bf2f(a1.y) + bf2f(a2.y);
            y.z += bf2f(a0.z) + bf2f(a1.z) + bf2f(a2.z);
            y.w += bf2f(a0.w) + bf2f(a1.w) + bf2f(a2.w);
            ((float4*)(ent_res + (size_t)row * D))[lane] = y;
        } else {
            ((ushort4*)(ent_out_b + (size_t)row * D))[lane] =
                make_ushort4(f2bf(y.x), f2bf(y.y), f2bf(y.z), f2bf(y.w));
        }
    } else {
        int u = row - n_ent;
        if (u >= n_users) return;
        int2 oc = oc_u[u];
        int s = oc.x, deg = oc.y;
        int end = s + deg;
        float4 base;
        if (hop == 1) base = ((const float4*)user0)[u * 64 + lane];
        else          base = ((const float4*)usr_res)[u * 64 + lane];
        float4 acc = make_float4(0.f, 0.f, 0.f, 0.f);
        for (int j = s; j < end; j += 8) {
            int e1 = end - 1;
            int2 mm[8];
            #pragma unroll
            for (int k = 0; k < 8; ++k) {
                int jj = j + k;
                mm[k] = uc[jj < end ? jj : e1];
            }
            ushort4 eb[8];
            #pragma unroll
            for (int k = 0; k < 8; ++k)
                eb[k] = srcv[(mm[k].x) * 64 + lane];
            __builtin_amdgcn_sched_barrier(0);   // keep all 8 gathers in flight
            #pragma unroll
            for (int k = 0; k < 8; ++k) {
                float wv = (j + k < end) ? __int_as_float(mm[k].y) : 0.0f;
                fma4u(acc, wv, eb[k]);
            }
        }
        float ss = acc.x * acc.x + acc.y * acc.y + acc.z * acc.z + acc.w * acc.w;
        #pragma unroll
        for (int o = 32; o >= 1; o >>= 1) ss += __shfl_down(ss, o);
        ss = __shfl(ss, 0);
        float nrm = sqrtf(ss);
        float dninv = 1.0f / ((nrm > EPSV) ? nrm : EPSV);
        float4 y;
        y.x = cleanf(acc.x * dninv) + base.x;
        y.y = cleanf(acc.y * dninv) + base.y;
        y.z = cleanf(acc.z * dninv) + base.z;
        y.w = cleanf(acc.w * dninv) + base.w;
        ((float4*)(usr_res + (size_t)u * D))[lane] = y;
    }
}

extern "C" void kernel_launch(void* const* d_in, const int* in_sizes, int n_in,
                              void* d_out, int out_size, void* d_ws, size_t ws_size,
                              hipStream_t stream) {
    const float* user_emb   = (const float*)d_in[0];
    const float* entity_emb = (const float*)d_in[1];
    const int*   edge_index = (const int*)d_in[2];
    const int*   edge_type  = (const int*)d_in[3];
    const float* omega      = (const float*)d_in[4];
    const int*   inter_edge = (const int*)d_in[5];
    const float* inter_w    = (const float*)d_in[6];
    const float* rel_emb    = (const float*)d_in[7];

    const int n_users = in_sizes[0] / D;
    const int n_ent   = in_sizes[1] / D;
    const int E       = in_sizes[3];
    const int IE      = in_sizes[6];

    const int* head = edge_index;
    const int* tail = edge_index + E;
    const int* iu   = inter_edge;
    const int* ii   = inter_edge + IE;

    // ---- workspace layout ----
    char* w = (char*)d_ws;
    size_t entBh = (size_t)n_ent * D * sizeof(unsigned short);   // bf16 table
    unsigned short* ent0b = (unsigned short*)w;  w += entBh;
    unsigned short* ent_a = (unsigned short*)w;  w += entBh;
    unsigned short* ent_b = (unsigned short*)w;  w += entBh;
    int2*  kg    = (int2*)w;   w += (size_t)E * sizeof(int2);
    int2*  ucsr  = (int2*)w;   w += (size_t)IE * sizeof(int2);
    // zero-init region: counts_e | counts_u | denom | denom2 (contiguous)
    int*   counts_e = (int*)w;   w += (size_t)n_ent * sizeof(int);
    int*   counts_u = (int*)w;   w += (size_t)n_users * sizeof(int);
    float* denom    = (float*)w; w += (size_t)n_ent * sizeof(float);
    float* denom2   = (float*)w; w += (size_t)n_ent * sizeof(float);
    size_t zeroB = ((size_t)n_ent * 3 + n_users) * sizeof(int);
    int2*  oc_e     = (int2*)w; w += (size_t)n_ent * sizeof(int2);
    int2*  oc_u     = (int2*)w; w += (size_t)n_users * sizeof(int2);
    int*   cursor_e = (int*)w; w += (size_t)n_ent * sizeof(int);
    int*   cursor_u = (int*)w; w += (size_t)n_users * sizeof(int);

    float* ent_res = (float*)d_out;
    float* usr_res = (float*)d_out + (size_t)n_ent * D;

    hipMemsetAsync(counts_e, 0, zeroB, stream);

    // ---- fused: bf16 convert + counts + omega denominators ----
    int n4  = n_ent * (D / 4);
    int nbc = (n4 + 255) / 256;
    int total_edges = E + IE;
    int eb = (total_edges + 255) / 256;
    k_pre<<<nbc + eb, 256, 0, stream>>>(
        (const float4*)entity_emb, (ushort4*)ent0b, n4, nbc,
        head, omega, iu, counts_e, counts_u, denom, E, IE);

    // ---- single-launch scans -> packed {off,cnt} + cursors ----
    k_scan<<<2, 1024, 0, stream>>>(counts_e, oc_e, cursor_e, n_ent,
                                   counts_u, oc_u, cursor_u, n_users);

    // ---- fill CSR (packed, alpha inline, eta denominator) ----
    k_fill_both<<<eb, 256, 0, stream>>>(head, tail, edge_type, omega, iu, ii,
                                        inter_w, denom, denom2,
                                        cursor_e, cursor_u, kg, ucsr, E, IE);

    // ---- hops ----
    size_t waves = (size_t)n_ent + n_users;
    int gb = (int)((waves * 64 + 255) / 256);

    // hop 1: src=ent0b -> ent_a;  usr_res = user_emb + y
    k_hop<<<gb, 256, 0, stream>>>(oc_e, kg, oc_u, ucsr,
                                  denom2, rel_emb, ent0b, ent0b, ent_a, ent_b,
                                  ent_a, ent_res, user_emb, usr_res,
                                  n_ent, n_users, 1);
    // hop 2: src=ent_a -> ent_b;  usr_res += y
    k_hop<<<gb, 256, 0, stream>>>(oc_e, kg, oc_u, ucsr,
                                  denom2, rel_emb, ent_a, ent0b, ent_a, ent_b,
                                  ent_b, ent_res, user_emb, usr_res,
                                  n_ent, n_users, 2);
    // hop 3: src=ent_b; ent_res = ent0 + y1 + y2 + y (eta);  usr_res += y
    k_hop<<<gb, 256, 0, stream>>>(oc_e, kg, oc_u, ucsr,
                                  denom2, rel_emb, ent_b, ent0b, ent_a, ent_b,
                                  ent_b /*unused*/, ent_res, user_emb, usr_res,
                                  n_ent, n_users, 3);
}

// Round 5
// 617.119 us; speedup vs baseline: 1.3393x; 1.3393x over previous
//
#include <hip/hip_runtime.h>
#include <math.h>

#define D 256
#define EPSV 1e-8f
#define GAMMAV 0.2f
#define SCAN_B 256

typedef float f32x2 __attribute__((ext_vector_type(2)));

__device__ __forceinline__ float cleanf(float x) {
    if (isnan(x)) return 0.0f;
    if (isinf(x)) return x > 0.0f ? 10000.0f : 0.0001f;
    return x;
}

// bf16 <-> f32 (RNE on the way down; exact on the way up)
__device__ __forceinline__ unsigned short f2bf(float x) {
    unsigned u = __float_as_uint(x);
    return (unsigned short)((u + 0x7FFFu + ((u >> 16) & 1u)) >> 16);
}
__device__ __forceinline__ float bf2f(unsigned short b) {
    return __uint_as_float(((unsigned)b) << 16);
}

// edge weight: alpha (hops 1,2) or eta (hop 3)
__device__ __forceinline__ float ewgt(int bits, bool eta, float den2i) {
    float a = __int_as_float(bits);
    return eta ? ((a > GAMMAV) ? a * den2i : 0.0f) : a;
}

// unpack u32 holding 2 bf16 -> f32x2
__device__ __forceinline__ f32x2 bfpair(unsigned u) {
    f32x2 p;
    p.x = __uint_as_float(u << 16);
    p.y = __uint_as_float(u & 0xFFFF0000u);
    return p;
}

// VOP3P packed f32: ALL operands must be 64-bit VGPR pairs (R3 lesson:
// a single-VGPR scalar src is an invalid operand even with op_sel).
// acc += w2 * (e .* r)
__device__ __forceinline__ void pk_wfma(f32x2& acc, f32x2 w2, f32x2 e, f32x2 r) {
    f32x2 t;
    asm("v_pk_mul_f32 %0, %1, %2" : "=v"(t) : "v"(e), "v"(r));
    asm("v_pk_fma_f32 %0, %1, %2, %0" : "+v"(acc) : "v"(w2), "v"(t));
}
// acc += w2 * e
__device__ __forceinline__ void pk_wadd(f32x2& acc, f32x2 w2, f32x2 e) {
    asm("v_pk_fma_f32 %0, %1, %2, %0" : "+v"(acc) : "v"(w2), "v"(e));
}

// ---- fused: fp32->bf16 table convert + counting + omega denominator ---

__global__ __launch_bounds__(256) void k_pre(
    const float4* __restrict__ ein, ushort4* __restrict__ eout, int n4, int nbc,
    const int* __restrict__ head, const float* __restrict__ omega,
    const int* __restrict__ iu,
    int* __restrict__ counts_e, int* __restrict__ counts_u,
    float* __restrict__ denom, int E, int IE) {
    if ((int)blockIdx.x < nbc) {
        int i = blockIdx.x * 256 + threadIdx.x;
        if (i < n4) {
            float4 v = ein[i];
            eout[i] = make_ushort4(f2bf(v.x), f2bf(v.y), f2bf(v.z), f2bf(v.w));
        }
    } else {
        int i = (blockIdx.x - nbc) * 256 + threadIdx.x;
        if (i < E) {
            int h = head[i];
            atomicAdd(&counts_e[h], 1);
            atomicAdd(&denom[h], omega[i]);
        } else if (i < E + IE) {
            atomicAdd(&counts_u[iu[i - E]], 1);
        }
    }
}

// ---- hierarchical exclusive scan (3 small wide launches) --------------

__global__ __launch_bounds__(SCAN_B) void k_scan1(
    const int* __restrict__ ce, int* __restrict__ oe, int* __restrict__ be,
    int nE, int nbE,
    const int* __restrict__ cu, int* __restrict__ ou, int* __restrict__ bu,
    int nU) {
    __shared__ int tmp[SCAN_B];
    const int* in; int* out; int* bs; int n; int lb;
    if ((int)blockIdx.x < nbE) { in = ce; out = oe; bs = be; n = nE; lb = blockIdx.x; }
    else { in = cu; out = ou; bs = bu; n = nU; lb = blockIdx.x - nbE; }
    int i = lb * SCAN_B + threadIdx.x;
    int v = (i < n) ? in[i] : 0;
    tmp[threadIdx.x] = v;
    __syncthreads();
    for (int o = 1; o < SCAN_B; o <<= 1) {
        int t = (threadIdx.x >= (unsigned)o) ? tmp[threadIdx.x - o] : 0;
        __syncthreads();
        tmp[threadIdx.x] += t;
        __syncthreads();
    }
    if (i < n) out[i] = tmp[threadIdx.x] - v;   // exclusive (within block)
    if (threadIdx.x == SCAN_B - 1) bs[lb] = tmp[threadIdx.x];
}

__global__ __launch_bounds__(1024) void k_scan2(
    int* __restrict__ be, int nbE, int* __restrict__ bu, int nbU) {
    __shared__ int tmp[1024];
    int* bs = (blockIdx.x == 0) ? be : bu;
    int nb  = (blockIdx.x == 0) ? nbE : nbU;
    int v = ((int)threadIdx.x < nb) ? bs[threadIdx.x] : 0;
    tmp[threadIdx.x] = v;
    __syncthreads();
    for (int o = 1; o < 1024; o <<= 1) {
        int t = (threadIdx.x >= (unsigned)o) ? tmp[threadIdx.x - o] : 0;
        __syncthreads();
        tmp[threadIdx.x] += t;
        __syncthreads();
    }
    if ((int)threadIdx.x < nb) bs[threadIdx.x] = tmp[threadIdx.x] - v;  // exclusive
}

// adds block base, packs {off,cnt}, seeds cursor
__global__ __launch_bounds__(SCAN_B) void k_scan3(
    const int* __restrict__ oe, const int* __restrict__ ce,
    int2* __restrict__ oce, int* __restrict__ cure, const int* __restrict__ be,
    int nE, int nbE,
    const int* __restrict__ ou, const int* __restrict__ cu,
    int2* __restrict__ ocu, int* __restrict__ curu, const int* __restrict__ bu,
    int nU) {
    const int* out; const int* cnt; int2* oc; int* cur; const int* bs; int n; int lb;
    if ((int)blockIdx.x < nbE) {
        out = oe; cnt = ce; oc = oce; cur = cure; bs = be; n = nE; lb = blockIdx.x;
    } else {
        out = ou; cnt = cu; oc = ocu; cur = curu; bs = bu; n = nU; lb = blockIdx.x - nbE;
    }
    int i = lb * SCAN_B + threadIdx.x;
    if (i < n) {
        int v = out[i] + bs[lb];
        oc[i] = make_int2(v, cnt[i]);
        cur[i] = v;
    }
}

// ---- CSR fill: packed meta + inline alpha + eta denominator -----------

__global__ __launch_bounds__(256) void k_fill_both(
    const int* __restrict__ head, const int* __restrict__ tail,
    const int* __restrict__ etype, const float* __restrict__ omega,
    const int* __restrict__ iu, const int* __restrict__ ii,
    const float* __restrict__ iw,
    const float* __restrict__ denom, float* __restrict__ denom2,
    int* __restrict__ cursor_e, int* __restrict__ cursor_u,
    int2* __restrict__ kg, int2* __restrict__ uc, int E, int IE) {
    int i = blockIdx.x * blockDim.x + threadIdx.x;
    if (i < E) {
        int h = head[i];
        float a = omega[i] / (denom[h] + EPSV);
        int p = atomicAdd(&cursor_e[h], 1);
        int2 m;
        m.x = tail[i] | ((etype[i] - 1) << 20);   // tail < 2^20, rel < 2^5
        m.y = __float_as_int(a);
        kg[p] = m;
        if (a > GAMMAV) atomicAdd(&denom2[h], a);
    } else if (i < E + IE) {
        int e = i - E;
        int u = iu[e];
        int p = atomicAdd(&cursor_u[u], 1);
        int2 m;
        m.x = ii[e];
        m.y = __float_as_int(iw[e]);
        uc[p] = m;
    }
}

// ---- fused hop ---------------------------------------------------------
// waves [0, n_ent)            : entity rows
// waves [n_ent, n_ent+n_users): user rows
// Inner math uses v_pk_mul_f32 / v_pk_fma_f32 (2 floats per instr; weight
// splatted to a VGPR pair) -> fewer VALU instructions per edge.

__global__ __launch_bounds__(256) void k_hop(
    const int2* __restrict__ oc_e, const int2* __restrict__ kg,
    const int2* __restrict__ oc_u, const int2* __restrict__ uc,
    const float* __restrict__ denom2,
    const float* __restrict__ rel,              // fp32 (tiny, cached)
    const unsigned short* __restrict__ src,     // bf16 entity features
    const unsigned short* __restrict__ ent0b,   // bf16 entity_emb (hop3)
    const unsigned short* __restrict__ y1b,     // bf16 hop-1 output (hop3)
    const unsigned short* __restrict__ y2b,     // bf16 hop-2 output (hop3)
    unsigned short* __restrict__ ent_out_b,     // bf16 dst (hops 1,2)
    float* __restrict__ ent_res,                // fp32 dst (hop3)
    const float* __restrict__ user0,
    float* __restrict__ usr_res,
    int n_ent, int n_users, int hop) {
    int row  = (int)((blockIdx.x * (size_t)blockDim.x + threadIdx.x) >> 6);
    int lane = threadIdx.x & 63;
    const uint2*  srcv = (const uint2*)src;      // 8 B/lane = one bf16x4 chunk
    const float4* relv = (const float4*)rel;
    if (row < n_ent) {
        int2 oc = oc_e[row];
        int s = oc.x, deg = oc.y;
        int end = s + deg;
        const bool eta = (hop == 3);
        float den2i = 0.0f;
        ushort4 a0, a1, a2;
        if (eta) {
            den2i = 1.0f / (denom2[row] + EPSV);
            a0 = ((const ushort4*)ent0b)[row * 64 + lane];
            a1 = ((const ushort4*)y1b )[row * 64 + lane];
            a2 = ((const ushort4*)y2b )[row * 64 + lane];
        }
        f32x2 accA = {0.f, 0.f}, accB = {0.f, 0.f};
        for (int j = s; j < end; j += 4) {
            int e1 = end - 1;
            int j1 = (j + 1 < end) ? j + 1 : e1;
            int j2 = (j + 2 < end) ? j + 2 : e1;
            int j3 = (j + 3 < end) ? j + 3 : e1;
            int2 m0 = kg[j];
            int2 m1 = kg[j1];
            int2 m2 = kg[j2];
            int2 m3 = kg[j3];
            uint2 e0 = srcv[(m0.x & 0xFFFFF) * 64 + lane];
            uint2 eb1 = srcv[(m1.x & 0xFFFFF) * 64 + lane];
            uint2 eb2 = srcv[(m2.x & 0xFFFFF) * 64 + lane];
            uint2 eb3 = srcv[(m3.x & 0xFFFFF) * 64 + lane];
            float4 rw0 = relv[(((unsigned)m0.x) >> 20) * 64 + lane];
            float4 rw1 = relv[(((unsigned)m1.x) >> 20) * 64 + lane];
            float4 rw2 = relv[(((unsigned)m2.x) >> 20) * 64 + lane];
            float4 rw3 = relv[(((unsigned)m3.x) >> 20) * 64 + lane];
            __builtin_amdgcn_sched_barrier(0);   // keep all 8 gathers in flight
            float w0 = ewgt(m0.y, eta, den2i);
            float w1 = (j + 1 < end) ? ewgt(m1.y, eta, den2i) : 0.0f;
            float w2 = (j + 2 < end) ? ewgt(m2.y, eta, den2i) : 0.0f;
            float w3 = (j + 3 < end) ? ewgt(m3.y, eta, den2i) : 0.0f;
            f32x2 ww, rA, rB;
            ww.x = w0; ww.y = w0;
            rA.x = rw0.x; rA.y = rw0.y; rB.x = rw0.z; rB.y = rw0.w;
            pk_wfma(accA, ww, bfpair(e0.x), rA);
            pk_wfma(accB, ww, bfpair(e0.y), rB);
            ww.x = w1; ww.y = w1;
            rA.x = rw1.x; rA.y = rw1.y; rB.x = rw1.z; rB.y = rw1.w;
            pk_wfma(accA, ww, bfpair(eb1.x), rA);
            pk_wfma(accB, ww, bfpair(eb1.y), rB);
            ww.x = w2; ww.y = w2;
            rA.x = rw2.x; rA.y = rw2.y; rB.x = rw2.z; rB.y = rw2.w;
            pk_wfma(accA, ww, bfpair(eb2.x), rA);
            pk_wfma(accB, ww, bfpair(eb2.y), rB);
            ww.x = w3; ww.y = w3;
            rA.x = rw3.x; rA.y = rw3.y; rB.x = rw3.z; rB.y = rw3.w;
            pk_wfma(accA, ww, bfpair(eb3.x), rA);
            pk_wfma(accB, ww, bfpair(eb3.y), rB);
        }
        float cinv = 1.0f / ((deg > 0) ? (float)deg : 1.0f);
        float4 acc;
        acc.x = accA.x * cinv; acc.y = accA.y * cinv;
        acc.z = accB.x * cinv; acc.w = accB.y * cinv;
        float ss = acc.x * acc.x + acc.y * acc.y + acc.z * acc.z + acc.w * acc.w;
        #pragma unroll
        for (int o = 32; o >= 1; o >>= 1) ss += __shfl_down(ss, o);
        ss = __shfl(ss, 0);
        float nrm = sqrtf(ss);
        float dninv = 1.0f / ((nrm > EPSV) ? nrm : EPSV);
        float4 y;
        y.x = cleanf(acc.x * dninv);
        y.y = cleanf(acc.y * dninv);
        y.z = cleanf(acc.z * dninv);
        y.w = cleanf(acc.w * dninv);
        if (hop == 3) {
            y.x += bf2f(a0.x) + bf2f(a1.x) + bf2f(a2.x);
            y.y += bf2f(a0.y) + bf2f(a1.y) + bf2f(a2.y);
            y.z += bf2f(a0.z) + bf2f(a1.z) + bf2f(a2.z);
            y.w += bf2f(a0.w) + bf2f(a1.w) + bf2f(a2.w);
            ((float4*)(ent_res + (size_t)row * D))[lane] = y;
        } else {
            ((ushort4*)(ent_out_b + (size_t)row * D))[lane] =
                make_ushort4(f2bf(y.x), f2bf(y.y), f2bf(y.z), f2bf(y.w));
        }
    } else {
        int u = row - n_ent;
        if (u >= n_users) return;
        int2 oc = oc_u[u];
        int s = oc.x, deg = oc.y;
        int end = s + deg;
        float4 base;
        if (hop == 1) base = ((const float4*)user0)[u * 64 + lane];
        else          base = ((const float4*)usr_res)[u * 64 + lane];
        f32x2 accA = {0.f, 0.f}, accB = {0.f, 0.f};
        for (int j = s; j < end; j += 8) {
            int e1 = end - 1;
            int2 mm[8];
            #pragma unroll
            for (int k = 0; k < 8; ++k) {
                int jj = j + k;
                mm[k] = uc[jj < end ? jj : e1];
            }
            uint2 eb[8];
            #pragma unroll
            for (int k = 0; k < 8; ++k)
                eb[k] = srcv[mm[k].x * 64 + lane];
            __builtin_amdgcn_sched_barrier(0);   // keep all 8 gathers in flight
            #pragma unroll
            for (int k = 0; k < 8; ++k) {
                float wv = (j + k < end) ? __int_as_float(mm[k].y) : 0.0f;
                f32x2 ww; ww.x = wv; ww.y = wv;
                pk_wadd(accA, ww, bfpair(eb[k].x));
                pk_wadd(accB, ww, bfpair(eb[k].y));
            }
        }
        float4 acc;
        acc.x = accA.x; acc.y = accA.y; acc.z = accB.x; acc.w = accB.y;
        float ss = acc.x * acc.x + acc.y * acc.y + acc.z * acc.z + acc.w * acc.w;
        #pragma unroll
        for (int o = 32; o >= 1; o >>= 1) ss += __shfl_down(ss, o);
        ss = __shfl(ss, 0);
        float nrm = sqrtf(ss);
        float dninv = 1.0f / ((nrm > EPSV) ? nrm : EPSV);
        float4 y;
        y.x = cleanf(acc.x * dninv) + base.x;
        y.y = cleanf(acc.y * dninv) + base.y;
        y.z = cleanf(acc.z * dninv) + base.z;
        y.w = cleanf(acc.w * dninv) + base.w;
        ((float4*)(usr_res + (size_t)u * D))[lane] = y;
    }
}

extern "C" void kernel_launch(void* const* d_in, const int* in_sizes, int n_in,
                              void* d_out, int out_size, void* d_ws, size_t ws_size,
                              hipStream_t stream) {
    const float* user_emb   = (const float*)d_in[0];
    const float* entity_emb = (const float*)d_in[1];
    const int*   edge_index = (const int*)d_in[2];
    const int*   edge_type  = (const int*)d_in[3];
    const float* omega      = (const float*)d_in[4];
    const int*   inter_edge = (const int*)d_in[5];
    const float* inter_w    = (const float*)d_in[6];
    const float* rel_emb    = (const float*)d_in[7];

    const int n_users = in_sizes[0] / D;
    const int n_ent   = in_sizes[1] / D;
    const int E       = in_sizes[3];
    const int IE      = in_sizes[6];

    const int* head = edge_index;
    const int* tail = edge_index + E;
    const int* iu   = inter_edge;
    const int* ii   = inter_edge + IE;

    // ---- workspace layout ----
    char* w = (char*)d_ws;
    size_t entBh = (size_t)n_ent * D * sizeof(unsigned short);   // bf16 table
    unsigned short* ent0b = (unsigned short*)w;  w += entBh;
    unsigned short* ent_a = (unsigned short*)w;  w += entBh;
    unsigned short* ent_b = (unsigned short*)w;  w += entBh;
    int2*  kg    = (int2*)w;   w += (size_t)E * sizeof(int2);
    int2*  ucsr  = (int2*)w;   w += (size_t)IE * sizeof(int2);
    // zero-init region: counts_e | counts_u | denom | denom2 (contiguous)
    int*   counts_e = (int*)w;   w += (size_t)n_ent * sizeof(int);
    int*   counts_u = (int*)w;   w += (size_t)n_users * sizeof(int);
    float* denom    = (float*)w; w += (size_t)n_ent * sizeof(float);
    float* denom2   = (float*)w; w += (size_t)n_ent * sizeof(float);
    size_t zeroB = ((size_t)n_ent * 3 + n_users) * sizeof(int);
    int*   offs_e   = (int*)w; w += (size_t)n_ent * sizeof(int);
    int*   offs_u   = (int*)w; w += (size_t)n_users * sizeof(int);
    int2*  oc_e     = (int2*)w; w += (size_t)n_ent * sizeof(int2);
    int2*  oc_u     = (int2*)w; w += (size_t)n_users * sizeof(int2);
    int*   cursor_e = (int*)w; w += (size_t)n_ent * sizeof(int);
    int*   cursor_u = (int*)w; w += (size_t)n_users * sizeof(int);
    int*   bsums_e  = (int*)w; w += 1024 * sizeof(int);
    int*   bsums_u  = (int*)w; w += 1024 * sizeof(int);

    float* ent_res = (float*)d_out;
    float* usr_res = (float*)d_out + (size_t)n_ent * D;

    hipMemsetAsync(counts_e, 0, zeroB, stream);

    // ---- fused: bf16 convert + counts + omega denominators ----
    int n4  = n_ent * (D / 4);
    int nbc = (n4 + 255) / 256;
    int total_edges = E + IE;
    int eb = (total_edges + 255) / 256;
    k_pre<<<nbc + eb, 256, 0, stream>>>(
        (const float4*)entity_emb, (ushort4*)ent0b, n4, nbc,
        head, omega, iu, counts_e, counts_u, denom, E, IE);

    // ---- hierarchical scans -> packed {off,cnt} + cursors ----
    int nbE = (n_ent + SCAN_B - 1) / SCAN_B;
    int nbU = (n_users + SCAN_B - 1) / SCAN_B;
    k_scan1<<<nbE + nbU, SCAN_B, 0, stream>>>(counts_e, offs_e, bsums_e, n_ent, nbE,
                                              counts_u, offs_u, bsums_u, n_users);
    k_scan2<<<2, 1024, 0, stream>>>(bsums_e, nbE, bsums_u, nbU);
    k_scan3<<<nbE + nbU, SCAN_B, 0, stream>>>(offs_e, counts_e, oc_e, cursor_e,
                                              bsums_e, n_ent, nbE,
                                              offs_u, counts_u, oc_u, cursor_u,
                                              bsums_u, n_users);

    // ---- fill CSR (packed, alpha inline, eta denominator) ----
    k_fill_both<<<eb, 256, 0, stream>>>(head, tail, edge_type, omega, iu, ii,
                                        inter_w, denom, denom2,
                                        cursor_e, cursor_u, kg, ucsr, E, IE);

    // ---- hops ----
    size_t waves = (size_t)n_ent + n_users;
    int gb = (int)((waves * 64 + 255) / 256);

    // hop 1: src=ent0b -> ent_a;  usr_res = user_emb + y
    k_hop<<<gb, 256, 0, stream>>>(oc_e, kg, oc_u, ucsr,
                                  denom2, rel_emb, ent0b, ent0b, ent_a, ent_b,
                                  ent_a, ent_res, user_emb, usr_res,
                                  n_ent, n_users, 1);
    // hop 2: src=ent_a -> ent_b;  usr_res += y
    k_hop<<<gb, 256, 0, stream>>>(oc_e, kg, oc_u, ucsr,
                                  denom2, rel_emb, ent_a, ent0b, ent_a, ent_b,
                                  ent_b, ent_res, user_emb, usr_res,
                                  n_ent, n_users, 2);
    // hop 3: src=ent_b; ent_res = ent0 + y1 + y2 + y (eta);  usr_res += y
    k_hop<<<gb, 256, 0, stream>>>(oc_e, kg, oc_u, ucsr,
                                  denom2, rel_emb, ent_b, ent0b, ent_a, ent_b,
                                  ent_b /*unused*/, ent_res, user_emb, usr_res,
                                  n_ent, n_users, 3);
}

// Round 6
// 574.041 us; speedup vs baseline: 1.4398x; 1.0750x over previous
//
#include <hip/hip_runtime.h>
#include <math.h>

#define D 256
#define EPSV 1e-8f
#define GAMMAV 0.2f
#define SCAN_B 256

typedef float f32x2 __attribute__((ext_vector_type(2)));

__device__ __forceinline__ float cleanf(float x) {
    if (isnan(x)) return 0.0f;
    if (isinf(x)) return x > 0.0f ? 10000.0f : 0.0001f;
    return x;
}

// bf16 <-> f32 (RNE on the way down; exact on the way up)
__device__ __forceinline__ unsigned short f2bf(float x) {
    unsigned u = __float_as_uint(x);
    return (unsigned short)((u + 0x7FFFu + ((u >> 16) & 1u)) >> 16);
}
__device__ __forceinline__ float bf2f(unsigned short b) {
    return __uint_as_float(((unsigned)b) << 16);
}

__device__ __forceinline__ int rfl(int v) { return __builtin_amdgcn_readfirstlane(v); }

// unpack u32 holding 2 bf16 -> f32x2
__device__ __forceinline__ f32x2 bfpair(unsigned u) {
    f32x2 p;
    p.x = __uint_as_float(u << 16);
    p.y = __uint_as_float(u & 0xFFFF0000u);
    return p;
}

// VOP3P packed f32: ALL operands must be 64-bit VGPR pairs.
// acc += w2 * (e .* r)
__device__ __forceinline__ void pk_wfma(f32x2& acc, f32x2 w2, f32x2 e, f32x2 r) {
    f32x2 t;
    asm("v_pk_mul_f32 %0, %1, %2" : "=v"(t) : "v"(e), "v"(r));
    asm("v_pk_fma_f32 %0, %1, %2, %0" : "+v"(acc) : "v"(w2), "v"(t));
}
// acc += w2 * e
__device__ __forceinline__ void pk_wadd(f32x2& acc, f32x2 w2, f32x2 e) {
    asm("v_pk_fma_f32 %0, %1, %2, %0" : "+v"(acc) : "v"(w2), "v"(e));
}

// ---- fused: fp32->bf16 table convert + counting + omega denominator ---

__global__ __launch_bounds__(256) void k_pre(
    const float4* __restrict__ ein, ushort4* __restrict__ eout, int n4, int nbc,
    const int* __restrict__ head, const float* __restrict__ omega,
    const int* __restrict__ iu,
    int* __restrict__ counts_e, int* __restrict__ counts_u,
    float* __restrict__ denom, int E, int IE) {
    if ((int)blockIdx.x < nbc) {
        int i = blockIdx.x * 256 + threadIdx.x;
        if (i < n4) {
            float4 v = ein[i];
            eout[i] = make_ushort4(f2bf(v.x), f2bf(v.y), f2bf(v.z), f2bf(v.w));
        }
    } else {
        int i = (blockIdx.x - nbc) * 256 + threadIdx.x;
        if (i < E) {
            int h = head[i];
            atomicAdd(&counts_e[h], 1);
            atomicAdd(&denom[h], omega[i]);
        } else if (i < E + IE) {
            atomicAdd(&counts_u[iu[i - E]], 1);
        }
    }
}

// ---- hierarchical exclusive scan (3 small wide launches) --------------

__global__ __launch_bounds__(SCAN_B) void k_scan1(
    const int* __restrict__ ce, int* __restrict__ oe, int* __restrict__ be,
    int nE, int nbE,
    const int* __restrict__ cu, int* __restrict__ ou, int* __restrict__ bu,
    int nU) {
    __shared__ int tmp[SCAN_B];
    const int* in; int* out; int* bs; int n; int lb;
    if ((int)blockIdx.x < nbE) { in = ce; out = oe; bs = be; n = nE; lb = blockIdx.x; }
    else { in = cu; out = ou; bs = bu; n = nU; lb = blockIdx.x - nbE; }
    int i = lb * SCAN_B + threadIdx.x;
    int v = (i < n) ? in[i] : 0;
    tmp[threadIdx.x] = v;
    __syncthreads();
    for (int o = 1; o < SCAN_B; o <<= 1) {
        int t = (threadIdx.x >= (unsigned)o) ? tmp[threadIdx.x - o] : 0;
        __syncthreads();
        tmp[threadIdx.x] += t;
        __syncthreads();
    }
    if (i < n) out[i] = tmp[threadIdx.x] - v;   // exclusive (within block)
    if (threadIdx.x == SCAN_B - 1) bs[lb] = tmp[threadIdx.x];
}

__global__ __launch_bounds__(1024) void k_scan2(
    int* __restrict__ be, int nbE, int* __restrict__ bu, int nbU) {
    __shared__ int tmp[1024];
    int* bs = (blockIdx.x == 0) ? be : bu;
    int nb  = (blockIdx.x == 0) ? nbE : nbU;
    int v = ((int)threadIdx.x < nb) ? bs[threadIdx.x] : 0;
    tmp[threadIdx.x] = v;
    __syncthreads();
    for (int o = 1; o < 1024; o <<= 1) {
        int t = (threadIdx.x >= (unsigned)o) ? tmp[threadIdx.x - o] : 0;
        __syncthreads();
        tmp[threadIdx.x] += t;
        __syncthreads();
    }
    if ((int)threadIdx.x < nb) bs[threadIdx.x] = tmp[threadIdx.x] - v;  // exclusive
}

// adds block base, packs {off,cnt}, seeds cursor
__global__ __launch_bounds__(SCAN_B) void k_scan3(
    const int* __restrict__ oe, const int* __restrict__ ce,
    int2* __restrict__ oce, int* __restrict__ cure, const int* __restrict__ be,
    int nE, int nbE,
    const int* __restrict__ ou, const int* __restrict__ cu,
    int2* __restrict__ ocu, int* __restrict__ curu, const int* __restrict__ bu,
    int nU) {
    const int* out; const int* cnt; int2* oc; int* cur; const int* bs; int n; int lb;
    if ((int)blockIdx.x < nbE) {
        out = oe; cnt = ce; oc = oce; cur = cure; bs = be; n = nE; lb = blockIdx.x;
    } else {
        out = ou; cnt = cu; oc = ocu; cur = curu; bs = bu; n = nU; lb = blockIdx.x - nbE;
    }
    int i = lb * SCAN_B + threadIdx.x;
    if (i < n) {
        int v = out[i] + bs[lb];
        oc[i] = make_int2(v, cnt[i]);
        cur[i] = v;
    }
}

// ---- CSR fill: packed meta + inline alpha + eta denominator -----------

__global__ __launch_bounds__(256) void k_fill_both(
    const int* __restrict__ head, const int* __restrict__ tail,
    const int* __restrict__ etype, const float* __restrict__ omega,
    const int* __restrict__ iu, const int* __restrict__ ii,
    const float* __restrict__ iw,
    const float* __restrict__ denom, float* __restrict__ denom2,
    int* __restrict__ cursor_e, int* __restrict__ cursor_u,
    int2* __restrict__ kg, int2* __restrict__ uc, int E, int IE) {
    int i = blockIdx.x * blockDim.x + threadIdx.x;
    if (i < E) {
        int h = head[i];
        float a = omega[i] / (denom[h] + EPSV);
        int p = atomicAdd(&cursor_e[h], 1);
        int2 m;
        m.x = tail[i] | ((etype[i] - 1) << 20);   // tail < 2^20, rel < 2^5
        m.y = __float_as_int(a);
        kg[p] = m;
        if (a > GAMMAV) atomicAdd(&denom2[h], a);
    } else if (i < E + IE) {
        int e = i - E;
        int u = iu[e];
        int p = atomicAdd(&cursor_u[u], 1);
        int2 m;
        m.x = ii[e];
        m.y = __float_as_int(iw[e]);
        uc[p] = m;
    }
}

// ---- fused hop ---------------------------------------------------------
// waves [0, n_ent)            : entity rows
// waves [n_ent, n_ent+n_users): user rows
// All wave-uniform values (row, CSR meta, tail/rel indices, weights) are
// forced into SGPRs via readfirstlane: meta loads become s_load (SMEM,
// constant cache, no VALU/VMEM cost), gather bases become SGPR + lane
// voffset, loop control becomes SALU. Only the feature gathers and the
// FMA math remain on the vector pipes.
// kg/ucsr are zero-padded by 8 entries so meta reads need no clamping
// (OOB weights are masked to 0; zero-pad tails gather row 0 harmlessly).

__global__ __launch_bounds__(256) void k_hop(
    const int2* __restrict__ oc_e, const int2* __restrict__ kg,
    const int2* __restrict__ oc_u, const int2* __restrict__ uc,
    const float* __restrict__ denom2,
    const float* __restrict__ rel,              // fp32 (tiny, cached)
    const unsigned short* __restrict__ src,     // bf16 entity features
    const unsigned short* __restrict__ ent0b,   // bf16 entity_emb (hop3)
    const unsigned short* __restrict__ y1b,     // bf16 hop-1 output (hop3)
    const unsigned short* __restrict__ y2b,     // bf16 hop-2 output (hop3)
    unsigned short* __restrict__ ent_out_b,     // bf16 dst (hops 1,2)
    float* __restrict__ ent_res,                // fp32 dst (hop3)
    const float* __restrict__ user0,
    float* __restrict__ usr_res,
    int n_ent, int n_users, int hop) {
    int gid  = blockIdx.x * blockDim.x + threadIdx.x;
    int row  = rfl(gid >> 6);
    int lane = threadIdx.x & 63;
    const uint2*  srcv = (const uint2*)src;      // 8 B/lane = one bf16x4 chunk
    const float4* relv = (const float4*)rel;
    if (row < n_ent) {
        int2 oc = oc_e[row];                     // uniform -> s_load
        int s   = rfl(oc.x);
        int deg = rfl(oc.y);
        int end = s + deg;
        const bool eta = (hop == 3);
        float den2i = 0.0f;
        ushort4 a0, a1, a2;
        if (eta) {
            den2i = 1.0f / (denom2[row] + EPSV);
            a0 = ((const ushort4*)ent0b)[row * 64 + lane];
            a1 = ((const ushort4*)y1b )[row * 64 + lane];
            a2 = ((const ushort4*)y2b )[row * 64 + lane];
        }
        f32x2 accA = {0.f, 0.f}, accB = {0.f, 0.f};
        for (int j = s; j < end; j += 4) {
            int2 m0 = kg[j];                     // uniform addr -> s_load
            int2 m1 = kg[j + 1];
            int2 m2 = kg[j + 2];
            int2 m3 = kg[j + 3];
            int x0 = rfl(m0.x), x1 = rfl(m1.x), x2 = rfl(m2.x), x3 = rfl(m3.x);
            int b0 = rfl(m0.y), b1 = rfl(m1.y), b2 = rfl(m2.y), b3 = rfl(m3.y);
            // SGPR base + lane voffset gathers
            uint2 e0 = (srcv + (size_t)(x0 & 0xFFFFF) * 64)[lane];
            uint2 e1 = (srcv + (size_t)(x1 & 0xFFFFF) * 64)[lane];
            uint2 e2 = (srcv + (size_t)(x2 & 0xFFFFF) * 64)[lane];
            uint2 e3 = (srcv + (size_t)(x3 & 0xFFFFF) * 64)[lane];
            float4 rw0 = (relv + (size_t)(((unsigned)x0) >> 20) * 64)[lane];
            float4 rw1 = (relv + (size_t)(((unsigned)x1) >> 20) * 64)[lane];
            float4 rw2 = (relv + (size_t)(((unsigned)x2) >> 20) * 64)[lane];
            float4 rw3 = (relv + (size_t)(((unsigned)x3) >> 20) * 64)[lane];
            __builtin_amdgcn_sched_barrier(0);   // keep all 8 gathers in flight
            // weights (scalar sources; masked by uniform bound check)
            float a_0 = __int_as_float(b0);
            float a_1 = (j + 1 < end) ? __int_as_float(b1) : 0.0f;
            float a_2 = (j + 2 < end) ? __int_as_float(b2) : 0.0f;
            float a_3 = (j + 3 < end) ? __int_as_float(b3) : 0.0f;
            float w0 = eta ? ((a_0 > GAMMAV) ? a_0 * den2i : 0.0f) : a_0;
            float w1 = eta ? ((a_1 > GAMMAV) ? a_1 * den2i : 0.0f) : a_1;
            float w2 = eta ? ((a_2 > GAMMAV) ? a_2 * den2i : 0.0f) : a_2;
            float w3 = eta ? ((a_3 > GAMMAV) ? a_3 * den2i : 0.0f) : a_3;
            f32x2 ww, rA, rB;
            ww.x = w0; ww.y = w0;
            rA.x = rw0.x; rA.y = rw0.y; rB.x = rw0.z; rB.y = rw0.w;
            pk_wfma(accA, ww, bfpair(e0.x), rA);
            pk_wfma(accB, ww, bfpair(e0.y), rB);
            ww.x = w1; ww.y = w1;
            rA.x = rw1.x; rA.y = rw1.y; rB.x = rw1.z; rB.y = rw1.w;
            pk_wfma(accA, ww, bfpair(e1.x), rA);
            pk_wfma(accB, ww, bfpair(e1.y), rB);
            ww.x = w2; ww.y = w2;
            rA.x = rw2.x; rA.y = rw2.y; rB.x = rw2.z; rB.y = rw2.w;
            pk_wfma(accA, ww, bfpair(e2.x), rA);
            pk_wfma(accB, ww, bfpair(e2.y), rB);
            ww.x = w3; ww.y = w3;
            rA.x = rw3.x; rA.y = rw3.y; rB.x = rw3.z; rB.y = rw3.w;
            pk_wfma(accA, ww, bfpair(e3.x), rA);
            pk_wfma(accB, ww, bfpair(e3.y), rB);
        }
        float cinv = 1.0f / ((deg > 0) ? (float)deg : 1.0f);
        float4 acc;
        acc.x = accA.x * cinv; acc.y = accA.y * cinv;
        acc.z = accB.x * cinv; acc.w = accB.y * cinv;
        float ss = acc.x * acc.x + acc.y * acc.y + acc.z * acc.z + acc.w * acc.w;
        #pragma unroll
        for (int o = 32; o >= 1; o >>= 1) ss += __shfl_down(ss, o);
        ss = __shfl(ss, 0);
        float nrm = sqrtf(ss);
        float dninv = 1.0f / ((nrm > EPSV) ? nrm : EPSV);
        float4 y;
        y.x = cleanf(acc.x * dninv);
        y.y = cleanf(acc.y * dninv);
        y.z = cleanf(acc.z * dninv);
        y.w = cleanf(acc.w * dninv);
        if (hop == 3) {
            y.x += bf2f(a0.x) + bf2f(a1.x) + bf2f(a2.x);
            y.y += bf2f(a0.y) + bf2f(a1.y) + bf2f(a2.y);
            y.z += bf2f(a0.z) + bf2f(a1.z) + bf2f(a2.z);
            y.w += bf2f(a0.w) + bf2f(a1.w) + bf2f(a2.w);
            ((float4*)(ent_res + (size_t)row * D))[lane] = y;
        } else {
            ((ushort4*)(ent_out_b + (size_t)row * D))[lane] =
                make_ushort4(f2bf(y.x), f2bf(y.y), f2bf(y.z), f2bf(y.w));
        }
    } else {
        int u = row - n_ent;
        if (u >= n_users) return;
        int2 oc = oc_u[u];                       // uniform -> s_load
        int s   = rfl(oc.x);
        int deg = rfl(oc.y);
        int end = s + deg;
        float4 base;
        if (hop == 1) base = ((const float4*)user0)[u * 64 + lane];
        else          base = ((const float4*)usr_res)[u * 64 + lane];
        f32x2 accA = {0.f, 0.f}, accB = {0.f, 0.f};
        for (int j = s; j < end; j += 8) {
            int xx[8], bb[8];
            #pragma unroll
            for (int k = 0; k < 8; ++k) {
                int2 m = uc[j + k];              // uniform addr -> s_load
                xx[k] = rfl(m.x);
                bb[k] = rfl(m.y);
            }
            uint2 eb[8];
            #pragma unroll
            for (int k = 0; k < 8; ++k)
                eb[k] = (srcv + (size_t)xx[k] * 64)[lane];
            __builtin_amdgcn_sched_barrier(0);   // keep all 8 gathers in flight
            #pragma unroll
            for (int k = 0; k < 8; ++k) {
                float wv = (j + k < end) ? __int_as_float(bb[k]) : 0.0f;
                f32x2 ww; ww.x = wv; ww.y = wv;
                pk_wadd(accA, ww, bfpair(eb[k].x));
                pk_wadd(accB, ww, bfpair(eb[k].y));
            }
        }
        float4 acc;
        acc.x = accA.x; acc.y = accA.y; acc.z = accB.x; acc.w = accB.y;
        float ss = acc.x * acc.x + acc.y * acc.y + acc.z * acc.z + acc.w * acc.w;
        #pragma unroll
        for (int o = 32; o >= 1; o >>= 1) ss += __shfl_down(ss, o);
        ss = __shfl(ss, 0);
        float nrm = sqrtf(ss);
        float dninv = 1.0f / ((nrm > EPSV) ? nrm : EPSV);
        float4 y;
        y.x = cleanf(acc.x * dninv) + base.x;
        y.y = cleanf(acc.y * dninv) + base.y;
        y.z = cleanf(acc.z * dninv) + base.z;
        y.w = cleanf(acc.w * dninv) + base.w;
        ((float4*)(usr_res + (size_t)u * D))[lane] = y;
    }
}

extern "C" void kernel_launch(void* const* d_in, const int* in_sizes, int n_in,
                              void* d_out, int out_size, void* d_ws, size_t ws_size,
                              hipStream_t stream) {
    const float* user_emb   = (const float*)d_in[0];
    const float* entity_emb = (const float*)d_in[1];
    const int*   edge_index = (const int*)d_in[2];
    const int*   edge_type  = (const int*)d_in[3];
    const float* omega      = (const float*)d_in[4];
    const int*   inter_edge = (const int*)d_in[5];
    const float* inter_w    = (const float*)d_in[6];
    const float* rel_emb    = (const float*)d_in[7];

    const int n_users = in_sizes[0] / D;
    const int n_ent   = in_sizes[1] / D;
    const int E       = in_sizes[3];
    const int IE      = in_sizes[6];

    const int* head = edge_index;
    const int* tail = edge_index + E;
    const int* iu   = inter_edge;
    const int* ii   = inter_edge + IE;

    // ---- workspace layout ----
    char* w = (char*)d_ws;
    size_t entBh = (size_t)n_ent * D * sizeof(unsigned short);   // bf16 table
    unsigned short* ent0b = (unsigned short*)w;  w += entBh;
    unsigned short* ent_a = (unsigned short*)w;  w += entBh;
    unsigned short* ent_b = (unsigned short*)w;  w += entBh;
    int2*  kg    = (int2*)w;   w += (size_t)(E + 8) * sizeof(int2);   // +8 zero pad
    int2*  ucsr  = (int2*)w;   w += (size_t)(IE + 8) * sizeof(int2);  // +8 zero pad
    // zero-init region: counts_e | counts_u | denom | denom2 (contiguous)
    int*   counts_e = (int*)w;   w += (size_t)n_ent * sizeof(int);
    int*   counts_u = (int*)w;   w += (size_t)n_users * sizeof(int);
    float* denom    = (float*)w; w += (size_t)n_ent * sizeof(float);
    float* denom2   = (float*)w; w += (size_t)n_ent * sizeof(float);
    size_t zeroB = ((size_t)n_ent * 3 + n_users) * sizeof(int);
    int*   offs_e   = (int*)w; w += (size_t)n_ent * sizeof(int);
    int*   offs_u   = (int*)w; w += (size_t)n_users * sizeof(int);
    int2*  oc_e     = (int2*)w; w += (size_t)n_ent * sizeof(int2);
    int2*  oc_u     = (int2*)w; w += (size_t)n_users * sizeof(int2);
    int*   cursor_e = (int*)w; w += (size_t)n_ent * sizeof(int);
    int*   cursor_u = (int*)w; w += (size_t)n_users * sizeof(int);
    int*   bsums_e  = (int*)w; w += 1024 * sizeof(int);
    int*   bsums_u  = (int*)w; w += 1024 * sizeof(int);

    float* ent_res = (float*)d_out;
    float* usr_res = (float*)d_out + (size_t)n_ent * D;

    hipMemsetAsync(counts_e, 0, zeroB, stream);
    hipMemsetAsync(kg + E, 0, 8 * sizeof(int2), stream);     // meta over-read pad
    hipMemsetAsync(ucsr + IE, 0, 8 * sizeof(int2), stream);  // meta over-read pad

    // ---- fused: bf16 convert + counts + omega denominators ----
    int n4  = n_ent * (D / 4);
    int nbc = (n4 + 255) / 256;
    int total_edges = E + IE;
    int eb = (total_edges + 255) / 256;
    k_pre<<<nbc + eb, 256, 0, stream>>>(
        (const float4*)entity_emb, (ushort4*)ent0b, n4, nbc,
        head, omega, iu, counts_e, counts_u, denom, E, IE);

    // ---- hierarchical scans -> packed {off,cnt} + cursors ----
    int nbE = (n_ent + SCAN_B - 1) / SCAN_B;
    int nbU = (n_users + SCAN_B - 1) / SCAN_B;
    k_scan1<<<nbE + nbU, SCAN_B, 0, stream>>>(counts_e, offs_e, bsums_e, n_ent, nbE,
                                              counts_u, offs_u, bsums_u, n_users);
    k_scan2<<<2, 1024, 0, stream>>>(bsums_e, nbE, bsums_u, nbU);
    k_scan3<<<nbE + nbU, SCAN_B, 0, stream>>>(offs_e, counts_e, oc_e, cursor_e,
                                              bsums_e, n_ent, nbE,
                                              offs_u, counts_u, oc_u, cursor_u,
                                              bsums_u, n_users);

    // ---- fill CSR (packed, alpha inline, eta denominator) ----
    k_fill_both<<<eb, 256, 0, stream>>>(head, tail, edge_type, omega, iu, ii,
                                        inter_w, denom, denom2,
                                        cursor_e, cursor_u, kg, ucsr, E, IE);

    // ---- hops ----
    size_t waves = (size_t)n_ent + n_users;
    int gb = (int)((waves * 64 + 255) / 256);

    // hop 1: src=ent0b -> ent_a;  usr_res = user_emb + y
    k_hop<<<gb, 256, 0, stream>>>(oc_e, kg, oc_u, ucsr,
                                  denom2, rel_emb, ent0b, ent0b, ent_a, ent_b,
                                  ent_a, ent_res, user_emb, usr_res,
                                  n_ent, n_users, 1);
    // hop 2: src=ent_a -> ent_b;  usr_res += y
    k_hop<<<gb, 256, 0, stream>>>(oc_e, kg, oc_u, ucsr,
                                  denom2, rel_emb, ent_a, ent0b, ent_a, ent_b,
                                  ent_b, ent_res, user_emb, usr_res,
                                  n_ent, n_users, 2);
    // hop 3: src=ent_b; ent_res = ent0 + y1 + y2 + y (eta);  usr_res += y
    k_hop<<<gb, 256, 0, stream>>>(oc_e, kg, oc_u, ucsr,
                                  denom2, rel_emb, ent_b, ent0b, ent_a, ent_b,
                                  ent_b /*unused*/, ent_res, user_emb, usr_res,
                                  n_ent, n_users, 3);
}

// Round 7
// 570.556 us; speedup vs baseline: 1.4486x; 1.0061x over previous
//
#include <hip/hip_runtime.h>
#include <math.h>

#define D 256
#define EPSV 1e-8f
#define GAMMAV 0.2f
#define SCAN_B 256

typedef float f32x2 __attribute__((ext_vector_type(2)));

__device__ __forceinline__ float cleanf(float x) {
    if (isnan(x)) return 0.0f;
    if (isinf(x)) return x > 0.0f ? 10000.0f : 0.0001f;
    return x;
}

// bf16 <-> f32 (RNE on the way down; exact on the way up)
__device__ __forceinline__ unsigned short f2bf(float x) {
    unsigned u = __float_as_uint(x);
    return (unsigned short)((u + 0x7FFFu + ((u >> 16) & 1u)) >> 16);
}
__device__ __forceinline__ float bf2f(unsigned short b) {
    return __uint_as_float(((unsigned)b) << 16);
}

__device__ __forceinline__ int rfl(int v) { return __builtin_amdgcn_readfirstlane(v); }

// unpack u32 holding 2 bf16 -> f32x2
__device__ __forceinline__ f32x2 bfpair(unsigned u) {
    f32x2 p;
    p.x = __uint_as_float(u << 16);
    p.y = __uint_as_float(u & 0xFFFF0000u);
    return p;
}

// VOP3P packed f32: ALL operands must be 64-bit VGPR pairs.
__device__ __forceinline__ void pk_wfma(f32x2& acc, f32x2 w2, f32x2 e, f32x2 r) {
    f32x2 t;
    asm("v_pk_mul_f32 %0, %1, %2" : "=v"(t) : "v"(e), "v"(r));
    asm("v_pk_fma_f32 %0, %1, %2, %0" : "+v"(acc) : "v"(w2), "v"(t));
}
__device__ __forceinline__ void pk_wadd(f32x2& acc, f32x2 w2, f32x2 e) {
    asm("v_pk_fma_f32 %0, %1, %2, %0" : "+v"(acc) : "v"(w2), "v"(e));
}

// ---- fused: fp32->bf16 table convert + counting + omega denominator ---

__global__ __launch_bounds__(256) void k_pre(
    const float4* __restrict__ ein, ushort4* __restrict__ eout, int n4, int nbc,
    const int* __restrict__ head, const float* __restrict__ omega,
    const int* __restrict__ iu,
    int* __restrict__ counts_e, int* __restrict__ counts_u,
    float* __restrict__ denom, int E, int IE) {
    if ((int)blockIdx.x < nbc) {
        int i = blockIdx.x * 256 + threadIdx.x;
        if (i < n4) {
            float4 v = ein[i];
            eout[i] = make_ushort4(f2bf(v.x), f2bf(v.y), f2bf(v.z), f2bf(v.w));
        }
    } else {
        int i = (blockIdx.x - nbc) * 256 + threadIdx.x;
        if (i < E) {
            int h = head[i];
            atomicAdd(&counts_e[h], 1);
            atomicAdd(&denom[h], omega[i]);
        } else if (i < E + IE) {
            atomicAdd(&counts_u[iu[i - E]], 1);
        }
    }
}

// ---- hierarchical exclusive scan (3 small wide launches) --------------

__global__ __launch_bounds__(SCAN_B) void k_scan1(
    const int* __restrict__ ce, int* __restrict__ oe, int* __restrict__ be,
    int nE, int nbE,
    const int* __restrict__ cu, int* __restrict__ ou, int* __restrict__ bu,
    int nU) {
    __shared__ int tmp[SCAN_B];
    const int* in; int* out; int* bs; int n; int lb;
    if ((int)blockIdx.x < nbE) { in = ce; out = oe; bs = be; n = nE; lb = blockIdx.x; }
    else { in = cu; out = ou; bs = bu; n = nU; lb = blockIdx.x - nbE; }
    int i = lb * SCAN_B + threadIdx.x;
    int v = (i < n) ? in[i] : 0;
    tmp[threadIdx.x] = v;
    __syncthreads();
    for (int o = 1; o < SCAN_B; o <<= 1) {
        int t = (threadIdx.x >= (unsigned)o) ? tmp[threadIdx.x - o] : 0;
        __syncthreads();
        tmp[threadIdx.x] += t;
        __syncthreads();
    }
    if (i < n) out[i] = tmp[threadIdx.x] - v;   // exclusive (within block)
    if (threadIdx.x == SCAN_B - 1) bs[lb] = tmp[threadIdx.x];
}

__global__ __launch_bounds__(1024) void k_scan2(
    int* __restrict__ be, int nbE, int* __restrict__ bu, int nbU) {
    __shared__ int tmp[1024];
    int* bs = (blockIdx.x == 0) ? be : bu;
    int nb  = (blockIdx.x == 0) ? nbE : nbU;
    int v = ((int)threadIdx.x < nb) ? bs[threadIdx.x] : 0;
    tmp[threadIdx.x] = v;
    __syncthreads();
    for (int o = 1; o < 1024; o <<= 1) {
        int t = (threadIdx.x >= (unsigned)o) ? tmp[threadIdx.x - o] : 0;
        __syncthreads();
        tmp[threadIdx.x] += t;
        __syncthreads();
    }
    if ((int)threadIdx.x < nb) bs[threadIdx.x] = tmp[threadIdx.x] - v;  // exclusive
}

// adds block base, packs {off,cnt}, seeds cursor
__global__ __launch_bounds__(SCAN_B) void k_scan3(
    const int* __restrict__ oe, const int* __restrict__ ce,
    int2* __restrict__ oce, int* __restrict__ cure, const int* __restrict__ be,
    int nE, int nbE,
    const int* __restrict__ ou, const int* __restrict__ cu,
    int2* __restrict__ ocu, int* __restrict__ curu, const int* __restrict__ bu,
    int nU) {
    const int* out; const int* cnt; int2* oc; int* cur; const int* bs; int n; int lb;
    if ((int)blockIdx.x < nbE) {
        out = oe; cnt = ce; oc = oce; cur = cure; bs = be; n = nE; lb = blockIdx.x;
    } else {
        out = ou; cnt = cu; oc = ocu; cur = curu; bs = bu; n = nU; lb = blockIdx.x - nbE;
    }
    int i = lb * SCAN_B + threadIdx.x;
    if (i < n) {
        int v = out[i] + bs[lb];
        oc[i] = make_int2(v, cnt[i]);
        cur[i] = v;
    }
}

// ---- CSR fill: packed meta + inline alpha + eta denominator -----------

__global__ __launch_bounds__(256) void k_fill_both(
    const int* __restrict__ head, const int* __restrict__ tail,
    const int* __restrict__ etype, const float* __restrict__ omega,
    const int* __restrict__ iu, const int* __restrict__ ii,
    const float* __restrict__ iw,
    const float* __restrict__ denom, float* __restrict__ denom2,
    int* __restrict__ cursor_e, int* __restrict__ cursor_u,
    int2* __restrict__ kg, int2* __restrict__ uc, int E, int IE) {
    int i = blockIdx.x * blockDim.x + threadIdx.x;
    if (i < E) {
        int h = head[i];
        float a = omega[i] / (denom[h] + EPSV);
        int p = atomicAdd(&cursor_e[h], 1);
        int2 m;
        m.x = tail[i] | ((etype[i] - 1) << 20);   // tail < 2^20, rel < 2^5
        m.y = __float_as_int(a);
        kg[p] = m;
        if (a > GAMMAV) atomicAdd(&denom2[h], a);
    } else if (i < E + IE) {
        int e = i - E;
        int u = iu[e];
        int p = atomicAdd(&cursor_u[u], 1);
        int2 m;
        m.x = ii[e];
        m.y = __float_as_int(iw[e]);
        uc[p] = m;
    }
}

// ---- fused hop ---------------------------------------------------------
// TWO rows per wave, batches interleaved: issue row0's 4 metas+8 gathers,
// then row1's, then consume both -> 2x memory-level parallelism per wave.
// Batch tails are CLAMPED to the row's last edge (scalar s_min): the
// duplicate gather is an L1 hit (weight masked to 0), instead of fetching
// the next row's random feature rows (~130 MB/hop of wasted fabric
// traffic in the unclamped R6 version).

__device__ __forceinline__ void ent_issue(
    const int2* __restrict__ kg, const uint2* __restrict__ srcv,
    const float4* __restrict__ relv, int j, int em1, int lane,
    uint2 (&f)[4], float4 (&q)[4], int (&b)[4]) {
    int2 m[4];
    #pragma unroll
    for (int k = 0; k < 4; ++k) {
        int jk = j + k; jk = (jk < em1) ? jk : em1;   // scalar clamp
        m[k] = kg[jk];                                // uniform -> s_load
    }
    #pragma unroll
    for (int k = 0; k < 4; ++k) {
        int x = rfl(m[k].x);
        b[k] = rfl(m[k].y);
        f[k] = (srcv + (size_t)(x & 0xFFFFF) * 64)[lane];
        q[k] = (relv + (size_t)(((unsigned)x) >> 20) * 64)[lane];
    }
}

__device__ __forceinline__ void ent_math(
    int j, int e, bool eta, float den2i,
    const uint2 (&f)[4], const float4 (&q)[4], const int (&b)[4],
    f32x2& accA, f32x2& accB) {
    #pragma unroll
    for (int k = 0; k < 4; ++k) {
        float aa = __int_as_float(b[k]);
        float w = eta ? ((aa > GAMMAV) ? aa * den2i : 0.0f) : aa;
        if (k) w = (j + k < e) ? w : 0.0f;
        f32x2 ww; ww.x = w; ww.y = w;
        f32x2 rA; rA.x = q[k].x; rA.y = q[k].y;
        f32x2 rB; rB.x = q[k].z; rB.y = q[k].w;
        pk_wfma(accA, ww, bfpair(f[k].x), rA);
        pk_wfma(accB, ww, bfpair(f[k].y), rB);
    }
}

__device__ __forceinline__ void usr_issue(
    const int2* __restrict__ uc, const uint2* __restrict__ srcv,
    int j, int em1, int lane, uint2 (&f)[8], int (&b)[8]) {
    int2 m[8];
    #pragma unroll
    for (int k = 0; k < 8; ++k) {
        int jk = j + k; jk = (jk < em1) ? jk : em1;
        m[k] = uc[jk];
    }
    #pragma unroll
    for (int k = 0; k < 8; ++k) {
        int x = rfl(m[k].x);
        b[k] = rfl(m[k].y);
        f[k] = (srcv + (size_t)x * 64)[lane];
    }
}

__device__ __forceinline__ void usr_math(
    int j, int e, const uint2 (&f)[8], const int (&b)[8],
    f32x2& accA, f32x2& accB) {
    #pragma unroll
    for (int k = 0; k < 8; ++k) {
        float w = __int_as_float(b[k]);
        if (k) w = (j + k < e) ? w : 0.0f;
        f32x2 ww; ww.x = w; ww.y = w;
        pk_wadd(accA, ww, bfpair(f[k].x));
        pk_wadd(accB, ww, bfpair(f[k].y));
    }
}

__device__ __forceinline__ void ent_epi(
    f32x2 accA, f32x2 accB, int deg, int hop,
    ushort4 a0, ushort4 a1, ushort4 a2,
    int row, int lane,
    unsigned short* __restrict__ ent_out_b, float* __restrict__ ent_res) {
    float cinv = 1.0f / ((deg > 0) ? (float)deg : 1.0f);
    float4 acc;
    acc.x = accA.x * cinv; acc.y = accA.y * cinv;
    acc.z = accB.x * cinv; acc.w = accB.y * cinv;
    float ss = acc.x * acc.x + acc.y * acc.y + acc.z * acc.z + acc.w * acc.w;
    #pragma unroll
    for (int o = 32; o >= 1; o >>= 1) ss += __shfl_down(ss, o);
    ss = __shfl(ss, 0);
    float nrm = sqrtf(ss);
    float dninv = 1.0f / ((nrm > EPSV) ? nrm : EPSV);
    float4 y;
    y.x = cleanf(acc.x * dninv);
    y.y = cleanf(acc.y * dninv);
    y.z = cleanf(acc.z * dninv);
    y.w = cleanf(acc.w * dninv);
    if (hop == 3) {
        y.x += bf2f(a0.x) + bf2f(a1.x) + bf2f(a2.x);
        y.y += bf2f(a0.y) + bf2f(a1.y) + bf2f(a2.y);
        y.z += bf2f(a0.z) + bf2f(a1.z) + bf2f(a2.z);
        y.w += bf2f(a0.w) + bf2f(a1.w) + bf2f(a2.w);
        ((float4*)(ent_res + (size_t)row * D))[lane] = y;
    } else {
        ((ushort4*)(ent_out_b + (size_t)row * D))[lane] =
            make_ushort4(f2bf(y.x), f2bf(y.y), f2bf(y.z), f2bf(y.w));
    }
}

__device__ __forceinline__ void usr_epi(
    f32x2 accA, f32x2 accB, float4 base, int u, int lane,
    float* __restrict__ usr_res) {
    float4 acc;
    acc.x = accA.x; acc.y = accA.y; acc.z = accB.x; acc.w = accB.y;
    float ss = acc.x * acc.x + acc.y * acc.y + acc.z * acc.z + acc.w * acc.w;
    #pragma unroll
    for (int o = 32; o >= 1; o >>= 1) ss += __shfl_down(ss, o);
    ss = __shfl(ss, 0);
    float nrm = sqrtf(ss);
    float dninv = 1.0f / ((nrm > EPSV) ? nrm : EPSV);
    float4 y;
    y.x = cleanf(acc.x * dninv) + base.x;
    y.y = cleanf(acc.y * dninv) + base.y;
    y.z = cleanf(acc.z * dninv) + base.z;
    y.w = cleanf(acc.w * dninv) + base.w;
    ((float4*)(usr_res + (size_t)u * D))[lane] = y;
}

__global__ __launch_bounds__(256) void k_hop(
    const int2* __restrict__ oc_e, const int2* __restrict__ kg,
    const int2* __restrict__ oc_u, const int2* __restrict__ uc,
    const float* __restrict__ denom2,
    const float* __restrict__ rel,
    const unsigned short* __restrict__ src,
    const unsigned short* __restrict__ ent0b,
    const unsigned short* __restrict__ y1b,
    const unsigned short* __restrict__ y2b,
    unsigned short* __restrict__ ent_out_b,
    float* __restrict__ ent_res,
    const float* __restrict__ user0,
    float* __restrict__ usr_res,
    int n_ent, int n_users, int hop) {
    int gid  = blockIdx.x * blockDim.x + threadIdx.x;
    int wid  = rfl(gid >> 6);
    int lane = threadIdx.x & 63;
    const uint2*  srcv = (const uint2*)src;
    const float4* relv = (const float4*)rel;
    int entW = (n_ent + 1) >> 1;
    if (wid < entW) {
        int r0 = wid * 2;
        int r1 = r0 + 1;
        bool v1 = r1 < n_ent;
        int2 oc0 = oc_e[r0];
        int s0 = rfl(oc0.x), d0 = rfl(oc0.y), e0 = s0 + d0;
        int s1 = 0, d1 = 0, e1 = 0;
        if (v1) {
            int2 oc1 = oc_e[r1];
            s1 = rfl(oc1.x); d1 = rfl(oc1.y); e1 = s1 + d1;
        }
        const bool eta = (hop == 3);
        float dn0 = 0.f, dn1 = 0.f;
        ushort4 a00, a01, a02, a10, a11, a12;
        if (eta) {
            dn0 = 1.0f / (denom2[r0] + EPSV);
            a00 = ((const ushort4*)ent0b)[r0 * 64 + lane];
            a01 = ((const ushort4*)y1b )[r0 * 64 + lane];
            a02 = ((const ushort4*)y2b )[r0 * 64 + lane];
            if (v1) {
                dn1 = 1.0f / (denom2[r1] + EPSV);
                a10 = ((const ushort4*)ent0b)[r1 * 64 + lane];
                a11 = ((const ushort4*)y1b )[r1 * 64 + lane];
                a12 = ((const ushort4*)y2b )[r1 * 64 + lane];
            }
        }
        f32x2 A0 = {0.f, 0.f}, B0 = {0.f, 0.f};
        f32x2 A1 = {0.f, 0.f}, B1 = {0.f, 0.f};
        int j0 = s0, j1 = s1;
        while ((j0 < e0) || (j1 < e1)) {
            bool g0 = j0 < e0, g1 = j1 < e1;   // wave-uniform
            uint2 f0[4], f1[4];
            float4 q0[4], q1[4];
            int b0[4], b1[4];
            if (g0) ent_issue(kg, srcv, relv, j0, e0 - 1, lane, f0, q0, b0);
            if (g1) ent_issue(kg, srcv, relv, j1, e1 - 1, lane, f1, q1, b1);
            __builtin_amdgcn_sched_barrier(0);
            if (g0) { ent_math(j0, e0, eta, dn0, f0, q0, b0, A0, B0); j0 += 4; }
            if (g1) { ent_math(j1, e1, eta, dn1, f1, q1, b1, A1, B1); j1 += 4; }
        }
        ent_epi(A0, B0, d0, hop, a00, a01, a02, r0, lane, ent_out_b, ent_res);
        if (v1)
            ent_epi(A1, B1, d1, hop, a10, a11, a12, r1, lane, ent_out_b, ent_res);
    } else {
        int uw = wid - entW;
        int u0 = uw * 2;
        if (u0 >= n_users) return;
        int u1 = u0 + 1;
        bool v1 = u1 < n_users;
        int2 oc0 = oc_u[u0];
        int s0 = rfl(oc0.x), d0 = rfl(oc0.y), e0 = s0 + d0;
        int s1 = 0, e1 = 0;
        if (v1) {
            int2 oc1 = oc_u[u1];
            s1 = rfl(oc1.x); e1 = s1 + rfl(oc1.y);
        }
        float4 base0, base1;
        const float4* bsrc = (hop == 1) ? (const float4*)user0 : (const float4*)usr_res;
        base0 = bsrc[u0 * 64 + lane];
        if (v1) base1 = bsrc[u1 * 64 + lane];
        f32x2 A0 = {0.f, 0.f}, B0 = {0.f, 0.f};
        f32x2 A1 = {0.f, 0.f}, B1 = {0.f, 0.f};
        int j0 = s0, j1 = s1;
        while ((j0 < e0) || (j1 < e1)) {
            bool g0 = j0 < e0, g1 = j1 < e1;
            uint2 f0[8], f1[8];
            int b0[8], b1[8];
            if (g0) usr_issue(uc, srcv, j0, e0 - 1, lane, f0, b0);
            if (g1) usr_issue(uc, srcv, j1, e1 - 1, lane, f1, b1);
            __builtin_amdgcn_sched_barrier(0);
            if (g0) { usr_math(j0, e0, f0, b0, A0, B0); j0 += 8; }
            if (g1) { usr_math(j1, e1, f1, b1, A1, B1); j1 += 8; }
        }
        usr_epi(A0, B0, base0, u0, lane, usr_res);
        if (v1) usr_epi(A1, B1, base1, u1, lane, usr_res);
    }
}

extern "C" void kernel_launch(void* const* d_in, const int* in_sizes, int n_in,
                              void* d_out, int out_size, void* d_ws, size_t ws_size,
                              hipStream_t stream) {
    const float* user_emb   = (const float*)d_in[0];
    const float* entity_emb = (const float*)d_in[1];
    const int*   edge_index = (const int*)d_in[2];
    const int*   edge_type  = (const int*)d_in[3];
    const float* omega      = (const float*)d_in[4];
    const int*   inter_edge = (const int*)d_in[5];
    const float* inter_w    = (const float*)d_in[6];
    const float* rel_emb    = (const float*)d_in[7];

    const int n_users = in_sizes[0] / D;
    const int n_ent   = in_sizes[1] / D;
    const int E       = in_sizes[3];
    const int IE      = in_sizes[6];

    const int* head = edge_index;
    const int* tail = edge_index + E;
    const int* iu   = inter_edge;
    const int* ii   = inter_edge + IE;

    // ---- workspace layout ----
    char* w = (char*)d_ws;
    size_t entBh = (size_t)n_ent * D * sizeof(unsigned short);   // bf16 table
    unsigned short* ent0b = (unsigned short*)w;  w += entBh;
    unsigned short* ent_a = (unsigned short*)w;  w += entBh;
    unsigned short* ent_b = (unsigned short*)w;  w += entBh;
    int2*  kg    = (int2*)w;   w += (size_t)E * sizeof(int2);
    int2*  ucsr  = (int2*)w;   w += (size_t)IE * sizeof(int2);
    // zero-init region: counts_e | counts_u | denom | denom2 (contiguous)
    int*   counts_e = (int*)w;   w += (size_t)n_ent * sizeof(int);
    int*   counts_u = (int*)w;   w += (size_t)n_users * sizeof(int);
    float* denom    = (float*)w; w += (size_t)n_ent * sizeof(float);
    float* denom2   = (float*)w; w += (size_t)n_ent * sizeof(float);
    size_t zeroB = ((size_t)n_ent * 3 + n_users) * sizeof(int);
    int*   offs_e   = (int*)w; w += (size_t)n_ent * sizeof(int);
    int*   offs_u   = (int*)w; w += (size_t)n_users * sizeof(int);
    int2*  oc_e     = (int2*)w; w += (size_t)n_ent * sizeof(int2);
    int2*  oc_u     = (int2*)w; w += (size_t)n_users * sizeof(int2);
    int*   cursor_e = (int*)w; w += (size_t)n_ent * sizeof(int);
    int*   cursor_u = (int*)w; w += (size_t)n_users * sizeof(int);
    int*   bsums_e  = (int*)w; w += 1024 * sizeof(int);
    int*   bsums_u  = (int*)w; w += 1024 * sizeof(int);

    float* ent_res = (float*)d_out;
    float* usr_res = (float*)d_out + (size_t)n_ent * D;

    hipMemsetAsync(counts_e, 0, zeroB, stream);

    // ---- fused: bf16 convert + counts + omega denominators ----
    int n4  = n_ent * (D / 4);
    int nbc = (n4 + 255) / 256;
    int total_edges = E + IE;
    int eb = (total_edges + 255) / 256;
    k_pre<<<nbc + eb, 256, 0, stream>>>(
        (const float4*)entity_emb, (ushort4*)ent0b, n4, nbc,
        head, omega, iu, counts_e, counts_u, denom, E, IE);

    // ---- hierarchical scans -> packed {off,cnt} + cursors ----
    int nbE = (n_ent + SCAN_B - 1) / SCAN_B;
    int nbU = (n_users + SCAN_B - 1) / SCAN_B;
    k_scan1<<<nbE + nbU, SCAN_B, 0, stream>>>(counts_e, offs_e, bsums_e, n_ent, nbE,
                                              counts_u, offs_u, bsums_u, n_users);
    k_scan2<<<2, 1024, 0, stream>>>(bsums_e, nbE, bsums_u, nbU);
    k_scan3<<<nbE + nbU, SCAN_B, 0, stream>>>(offs_e, counts_e, oc_e, cursor_e,
                                              bsums_e, n_ent, nbE,
                                              offs_u, counts_u, oc_u, cursor_u,
                                              bsums_u, n_users);

    // ---- fill CSR (packed, alpha inline, eta denominator) ----
    k_fill_both<<<eb, 256, 0, stream>>>(head, tail, edge_type, omega, iu, ii,
                                        inter_w, denom, denom2,
                                        cursor_e, cursor_u, kg, ucsr, E, IE);

    // ---- hops (2 rows per wave) ----
    int entW = (n_ent + 1) >> 1;
    int usrW = (n_users + 1) >> 1;
    size_t waves = (size_t)entW + usrW;
    int gb = (int)((waves * 64 + 255) / 256);

    // hop 1: src=ent0b -> ent_a;  usr_res = user_emb + y
    k_hop<<<gb, 256, 0, stream>>>(oc_e, kg, oc_u, ucsr,
                                  denom2, rel_emb, ent0b, ent0b, ent_a, ent_b,
                                  ent_a, ent_res, user_emb, usr_res,
                                  n_ent, n_users, 1);
    // hop 2: src=ent_a -> ent_b;  usr_res += y
    k_hop<<<gb, 256, 0, stream>>>(oc_e, kg, oc_u, ucsr,
                                  denom2, rel_emb, ent_a, ent0b, ent_a, ent_b,
                                  ent_b, ent_res, user_emb, usr_res,
                                  n_ent, n_users, 2);
    // hop 3: src=ent_b; ent_res = ent0 + y1 + y2 + y (eta);  usr_res += y
    k_hop<<<gb, 256, 0, stream>>>(oc_e, kg, oc_u, ucsr,
                                  denom2, rel_emb, ent_b, ent0b, ent_a, ent_b,
                                  ent_b /*unused*/, ent_res, user_emb, usr_res,
                                  n_ent, n_users, 3);
}